// Round 6
// baseline (2425.098 us; speedup 1.0000x reference)
//
#include <hip/hip_runtime.h>
#include <cstdint>

// ElmanRNN: B=64, T=1024, I=H=256, fp32.
//   layer: xp = X @ W_ih^T + b ; h_t = tanh(xp_t + h_{t-1} @ W_hh^T)
// Plan: GEMM0 (xp0 -> ws) ; scan0 (y0 -> d_out) ; GEMM1 (xp1 -> ws) ; scan1 (-> d_out)
// Requires ws_size >= 64 MB.
//
// R5 scan: 512 threads (8 waves, 2/SIMD). Thread (j=tid>>1, q=tid&1) owns
// W_hh[j][q*128..+127] = 32 float4 = 128 VGPRs. __launch_bounds__(512) ->
// 256-VGPR launchable cap: live set ~210 fits, so PIN'd weights can finally
// stay register-resident (R3/R4 at 128-cap: VGPR_Count 48/52 = weights
// streamed from L1/L2 at ~22 TB/s = the real bottleneck).
// Pair reduce = 1x shfl_xor. One barrier/step. 4-deep xp prefetch.

#define HDIM 256
#define TLEN 1024
#define BATCH 64

// ---------------------------------------------------------------------------
// Input-projection GEMM (unchanged from R1).
// ---------------------------------------------------------------------------
__global__ __launch_bounds__(256) void proj_gemm(
    const float* __restrict__ X,
    const float* __restrict__ W,
    const float* __restrict__ bias,
    float* __restrict__ C, int M)
{
    __shared__ __align__(16) float Ast[16][136];
    __shared__ __align__(16) float Bst[16][68];

    const int tid = threadIdx.x;
    const int tx  = tid & 15;
    const int ty  = tid >> 4;
    const int m0  = blockIdx.x * 128;
    const int n0  = blockIdx.y * 64;

    float acc[8][4];
#pragma unroll
    for (int i = 0; i < 8; ++i)
#pragma unroll
        for (int j = 0; j < 4; ++j) acc[i][j] = 0.f;

    const int ar = tid >> 1;
    const int ah = (tid & 1) * 8;
    const int bn = tid >> 2;
    const int bg = (tid & 3) * 4;

    for (int kc = 0; kc < 16; ++kc) {
        const int k0 = kc * 16;
        const float4 av0 = *reinterpret_cast<const float4*>(&X[(size_t)(m0 + ar) * HDIM + k0 + ah]);
        const float4 av1 = *reinterpret_cast<const float4*>(&X[(size_t)(m0 + ar) * HDIM + k0 + ah + 4]);
        const float4 bv  = *reinterpret_cast<const float4*>(&W[(size_t)(n0 + bn) * HDIM + k0 + bg]);
        __syncthreads();
        Ast[ah + 0][ar] = av0.x; Ast[ah + 1][ar] = av0.y;
        Ast[ah + 2][ar] = av0.z; Ast[ah + 3][ar] = av0.w;
        Ast[ah + 4][ar] = av1.x; Ast[ah + 5][ar] = av1.y;
        Ast[ah + 6][ar] = av1.z; Ast[ah + 7][ar] = av1.w;
        Bst[bg + 0][bn] = bv.x;  Bst[bg + 1][bn] = bv.y;
        Bst[bg + 2][bn] = bv.z;  Bst[bg + 3][bn] = bv.w;
        __syncthreads();
#pragma unroll
        for (int kk = 0; kk < 16; ++kk) {
            const float4 a0 = *reinterpret_cast<const float4*>(&Ast[kk][ty * 8]);
            const float4 a1 = *reinterpret_cast<const float4*>(&Ast[kk][ty * 8 + 4]);
            const float4 b4 = *reinterpret_cast<const float4*>(&Bst[kk][tx * 4]);
            const float av[8] = {a0.x, a0.y, a0.z, a0.w, a1.x, a1.y, a1.z, a1.w};
            const float bb[4] = {b4.x, b4.y, b4.z, b4.w};
#pragma unroll
            for (int i = 0; i < 8; ++i)
#pragma unroll
                for (int j = 0; j < 4; ++j)
                    acc[i][j] = fmaf(av[i], bb[j], acc[i][j]);
        }
    }

    const float4 bias4 = *reinterpret_cast<const float4*>(&bias[n0 + tx * 4]);
    const float bb[4] = {bias4.x, bias4.y, bias4.z, bias4.w};
#pragma unroll
    for (int i = 0; i < 8; ++i) {
        float4 o;
        o.x = acc[i][0] + bb[0];
        o.y = acc[i][1] + bb[1];
        o.z = acc[i][2] + bb[2];
        o.w = acc[i][3] + bb[3];
        *reinterpret_cast<float4*>(&C[(size_t)(m0 + ty * 8 + i) * HDIM + n0 + tx * 4]) = o;
    }
}

// ---------------------------------------------------------------------------
// R5 recurrent scan.
// ---------------------------------------------------------------------------
__device__ __forceinline__ float fast_tanh(float x)
{
    const float xc = fminf(fmaxf(x, -15.f), 15.f);
    const float e  = __expf(2.f * xc);
    return (e - 1.f) / (e + 1.f);
}

#define PIN4(V) asm volatile("" : "+v"((V).x), "+v"((V).y), "+v"((V).z), "+v"((V).w))

#define STEP4(WC, IDX, SACC)                                                  \
    {                                                                         \
        const float4 hh = *reinterpret_cast<const float4*>(hb + (IDX) * 4);   \
        SACC = fmaf((WC).x, hh.x, SACC); SACC = fmaf((WC).y, hh.y, SACC);     \
        SACC = fmaf((WC).z, hh.z, SACC); SACC = fmaf((WC).w, hh.w, SACC);     \
    }

__global__ __launch_bounds__(512) void elman_scan(
    const float* __restrict__ xp,   // [B, T, H]
    const float* __restrict__ Whh,  // [H, H]
    float* __restrict__ y,          // [B, T, H]
    int T)
{
    const int b   = blockIdx.x;
    const int tid = threadIdx.x;
    const int j   = tid >> 1;       // output index 0..255
    const int q   = tid & 1;        // K-half

    // W_hh[j][q*128 .. +127] in 32 pinned float4 registers (128 VGPR).
    const float4* wp = reinterpret_cast<const float4*>(Whh + (size_t)j * HDIM + q * 128);
    float4 w0  = wp[0],  w1  = wp[1],  w2  = wp[2],  w3  = wp[3];
    float4 w4  = wp[4],  w5  = wp[5],  w6  = wp[6],  w7  = wp[7];
    float4 w8  = wp[8],  w9  = wp[9],  w10 = wp[10], w11 = wp[11];
    float4 w12 = wp[12], w13 = wp[13], w14 = wp[14], w15 = wp[15];
    float4 w16 = wp[16], w17 = wp[17], w18 = wp[18], w19 = wp[19];
    float4 w20 = wp[20], w21 = wp[21], w22 = wp[22], w23 = wp[23];
    float4 w24 = wp[24], w25 = wp[25], w26 = wp[26], w27 = wp[27];
    float4 w28 = wp[28], w29 = wp[29], w30 = wp[30], w31 = wp[31];
    PIN4(w0);  PIN4(w1);  PIN4(w2);  PIN4(w3);
    PIN4(w4);  PIN4(w5);  PIN4(w6);  PIN4(w7);
    PIN4(w8);  PIN4(w9);  PIN4(w10); PIN4(w11);
    PIN4(w12); PIN4(w13); PIN4(w14); PIN4(w15);
    PIN4(w16); PIN4(w17); PIN4(w18); PIN4(w19);
    PIN4(w20); PIN4(w21); PIN4(w22); PIN4(w23);
    PIN4(w24); PIN4(w25); PIN4(w26); PIN4(w27);
    PIN4(w28); PIN4(w29); PIN4(w30); PIN4(w31);

    __shared__ __align__(16) float hbuf[2][HDIM];

    const float* xrow = xp + (size_t)b * T * HDIM;
    float*       yrow = y  + (size_t)b * T * HDIM;

    if (q == 0) hbuf[0][j] = 0.f;

    float xv[4];
#pragma unroll
    for (int p = 0; p < 4; ++p) xv[p] = xrow[(size_t)p * HDIM + j];

    __syncthreads();

    int cur = 0;
    for (int t = 0; t < T; t += 4) {
#pragma unroll
        for (int p = 0; p < 4; ++p) {
            int tf = t + p + 4; tf = (tf < T) ? tf : (T - 1);
            const float xnew = xrow[(size_t)tf * HDIM + j];

            const float* hb = &hbuf[cur][q * 128];
            float s0 = 0.f, s1 = 0.f, s2 = 0.f, s3 = 0.f;

            // first 16 float4 of h (<=64 temp VGPRs live at once)
            STEP4(w0,  0,  s0); STEP4(w1,  1,  s1);
            STEP4(w2,  2,  s2); STEP4(w3,  3,  s3);
            STEP4(w4,  4,  s0); STEP4(w5,  5,  s1);
            STEP4(w6,  6,  s2); STEP4(w7,  7,  s3);
            STEP4(w8,  8,  s0); STEP4(w9,  9,  s1);
            STEP4(w10, 10, s2); STEP4(w11, 11, s3);
            STEP4(w12, 12, s0); STEP4(w13, 13, s1);
            STEP4(w14, 14, s2); STEP4(w15, 15, s3);
            __builtin_amdgcn_sched_barrier(0);
            // second 16
            STEP4(w16, 16, s0); STEP4(w17, 17, s1);
            STEP4(w18, 18, s2); STEP4(w19, 19, s3);
            STEP4(w20, 20, s0); STEP4(w21, 21, s1);
            STEP4(w22, 22, s2); STEP4(w23, 23, s3);
            STEP4(w24, 24, s0); STEP4(w25, 25, s1);
            STEP4(w26, 26, s2); STEP4(w27, 27, s3);
            STEP4(w28, 28, s0); STEP4(w29, 29, s1);
            STEP4(w30, 30, s2); STEP4(w31, 31, s3);

            float s = (s0 + s1) + (s2 + s3);
            s += __shfl_xor(s, 1);                 // combine the two K-halves

            const float hn = fast_tanh(s + xv[p]);

            if (q == 0) hbuf[cur ^ 1][j] = hn;
            else        yrow[(size_t)(t + p) * HDIM + j] = hn;

            xv[p] = xnew;
            cur ^= 1;
            __syncthreads();
        }
    }
}

// ---------------------------------------------------------------------------
extern "C" void kernel_launch(void* const* d_in, const int* in_sizes, int n_in,
                              void* d_out, int out_size, void* d_ws, size_t ws_size,
                              hipStream_t stream)
{
    const float* x     = (const float*)d_in[0];
    const float* W_ih0 = (const float*)d_in[1];
    const float* b_ih0 = (const float*)d_in[2];
    const float* W_hh0 = (const float*)d_in[3];
    const float* W_ih1 = (const float*)d_in[4];
    const float* b_ih1 = (const float*)d_in[5];
    const float* W_hh1 = (const float*)d_in[6];

    float* out = (float*)d_out;
    float* xp  = (float*)d_ws;          // needs 64 MB

    const int M = BATCH * TLEN;
    dim3 ggrid(M / 128, HDIM / 64);

    proj_gemm<<<ggrid, 256, 0, stream>>>(x,   W_ih0, b_ih0, xp, M);
    elman_scan<<<BATCH, 512, 0, stream>>>(xp, W_hh0, out, TLEN);
    proj_gemm<<<ggrid, 256, 0, stream>>>(out, W_ih1, b_ih1, xp, M);
    elman_scan<<<BATCH, 512, 0, stream>>>(xp, W_hh1, out, TLEN);
}

// Round 8
// 2155.235 us; speedup vs baseline: 1.1252x; 1.1252x over previous
//
#include <hip/hip_runtime.h>
#include <cstdint>

// ElmanRNN: B=64, T=1024, I=H=256, fp32.
//   layer: xp = X @ W_ih^T + b ; h_t = tanh(xp_t + h_{t-1} @ W_hh^T)
// Plan: conv(W_hh0,1 -> fp16 in ws tail) ; GEMM0 ; scan0 ; GEMM1 ; scan1.
//
// R6/R7: scan is L2-weight-streaming-bound (R3: 256 KB/step/CU at ~143 B/cyc
// = 1790 cyc/step; regalloc refuses register-resident weights, R3-R5).
// Fix: stream fp16 weights (128 KB/step/CU) + v_dot2_f32_f16 (fdot2).
// h stays fp32 in padded LDS (R3 layout, 0 bank conflicts); cvt_pkrtz
// packs h pairs in-register. Fallback to fp32 scan if ws too small.
// R7 = R6 with the cvt_pkrtz/fdot2 vector-type mismatch fixed via bit_cast.

#define HDIM 256
#define TLEN 1024
#define BATCH 64
#define HQ 68   // padded LDS quarter stride (floats)

typedef _Float16 h2_t  __attribute__((ext_vector_type(2)));   // fdot2 operand
typedef __fp16   fp2_t __attribute__((ext_vector_type(2)));   // cvt_pkrtz result

// ---------------------------------------------------------------------------
// Input-projection GEMM (unchanged from R1).
// ---------------------------------------------------------------------------
__global__ __launch_bounds__(256) void proj_gemm(
    const float* __restrict__ X,
    const float* __restrict__ W,
    const float* __restrict__ bias,
    float* __restrict__ C, int M)
{
    __shared__ __align__(16) float Ast[16][136];
    __shared__ __align__(16) float Bst[16][68];

    const int tid = threadIdx.x;
    const int tx  = tid & 15;
    const int ty  = tid >> 4;
    const int m0  = blockIdx.x * 128;
    const int n0  = blockIdx.y * 64;

    float acc[8][4];
#pragma unroll
    for (int i = 0; i < 8; ++i)
#pragma unroll
        for (int j = 0; j < 4; ++j) acc[i][j] = 0.f;

    const int ar = tid >> 1;
    const int ah = (tid & 1) * 8;
    const int bn = tid >> 2;
    const int bg = (tid & 3) * 4;

    for (int kc = 0; kc < 16; ++kc) {
        const int k0 = kc * 16;
        const float4 av0 = *reinterpret_cast<const float4*>(&X[(size_t)(m0 + ar) * HDIM + k0 + ah]);
        const float4 av1 = *reinterpret_cast<const float4*>(&X[(size_t)(m0 + ar) * HDIM + k0 + ah + 4]);
        const float4 bv  = *reinterpret_cast<const float4*>(&W[(size_t)(n0 + bn) * HDIM + k0 + bg]);
        __syncthreads();
        Ast[ah + 0][ar] = av0.x; Ast[ah + 1][ar] = av0.y;
        Ast[ah + 2][ar] = av0.z; Ast[ah + 3][ar] = av0.w;
        Ast[ah + 4][ar] = av1.x; Ast[ah + 5][ar] = av1.y;
        Ast[ah + 6][ar] = av1.z; Ast[ah + 7][ar] = av1.w;
        Bst[bg + 0][bn] = bv.x;  Bst[bg + 1][bn] = bv.y;
        Bst[bg + 2][bn] = bv.z;  Bst[bg + 3][bn] = bv.w;
        __syncthreads();
#pragma unroll
        for (int kk = 0; kk < 16; ++kk) {
            const float4 a0 = *reinterpret_cast<const float4*>(&Ast[kk][ty * 8]);
            const float4 a1 = *reinterpret_cast<const float4*>(&Ast[kk][ty * 8 + 4]);
            const float4 b4 = *reinterpret_cast<const float4*>(&Bst[kk][tx * 4]);
            const float av[8] = {a0.x, a0.y, a0.z, a0.w, a1.x, a1.y, a1.z, a1.w};
            const float bb[4] = {b4.x, b4.y, b4.z, b4.w};
#pragma unroll
            for (int i = 0; i < 8; ++i)
#pragma unroll
                for (int j = 0; j < 4; ++j)
                    acc[i][j] = fmaf(av[i], bb[j], acc[i][j]);
        }
    }

    const float4 bias4 = *reinterpret_cast<const float4*>(&bias[n0 + tx * 4]);
    const float bb[4] = {bias4.x, bias4.y, bias4.z, bias4.w};
#pragma unroll
    for (int i = 0; i < 8; ++i) {
        float4 o;
        o.x = acc[i][0] + bb[0];
        o.y = acc[i][1] + bb[1];
        o.z = acc[i][2] + bb[2];
        o.w = acc[i][3] + bb[3];
        *reinterpret_cast<float4*>(&C[(size_t)(m0 + ty * 8 + i) * HDIM + n0 + tx * 4]) = o;
    }
}

// ---------------------------------------------------------------------------
// W_hh fp32 -> fp16 conversion (one-time, RNE).
// ---------------------------------------------------------------------------
__global__ __launch_bounds__(256) void conv_w16(
    const float* __restrict__ W, uint16_t* __restrict__ w16)
{
    const int i = blockIdx.x * 256 + threadIdx.x;   // 256 blocks x 256 thr = 64K
    union { _Float16 h; uint16_t u; } cv;
    cv.h = (_Float16)W[i];
    w16[i] = cv.u;
}

// ---------------------------------------------------------------------------
// Common helpers
// ---------------------------------------------------------------------------
__device__ __forceinline__ float fast_tanh(float x)
{
    const float xc = fminf(fmaxf(x, -15.f), 15.f);
    const float e  = __expf(2.f * xc);
    return (e - 1.f) / (e + 1.f);
}

__device__ __forceinline__ h2_t pack2(float a, float b)
{
    const fp2_t p = __builtin_amdgcn_cvt_pkrtz(a, b);
    return __builtin_bit_cast(h2_t, p);
}

__device__ __forceinline__ float dot2a(uint32_t wpk, h2_t hpk, float s)
{
    return __builtin_amdgcn_fdot2(__builtin_bit_cast(h2_t, wpk), hpk, s, false);
}

// ---------------------------------------------------------------------------
// R6 fp16-weight scan. R3 thread mapping: j = wave*16 + (lane>>2), q = lane&3.
// Weights streamed from global (L2-resident) as 8 x uint4 per thread per step.
// ---------------------------------------------------------------------------
__global__ __launch_bounds__(1024, 4) void elman_scan_f16(
    const float* __restrict__ xp,      // [B, T, H]
    const uint16_t* __restrict__ w16,  // [H, H] fp16
    float* __restrict__ y,             // [B, T, H]
    int T)
{
    const int b    = blockIdx.x;
    const int tid  = threadIdx.x;
    const int lane = tid & 63;
    const int wave = tid >> 6;
    const int j    = wave * 16 + (lane >> 2);
    const int q    = lane & 3;

    const uint4* wp = reinterpret_cast<const uint4*>(w16 + (size_t)j * HDIM + q * 64);

    __shared__ __align__(16) float hbuf[2][4 * HQ];

    const float* xrow = xp + (size_t)b * T * HDIM;
    float*       yrow = y  + (size_t)b * T * HDIM;

    const int hpos = (j >> 6) * HQ + (j & 63);
    if (q == 0) hbuf[0][hpos] = 0.f;

    float xv[4];
#pragma unroll
    for (int p = 0; p < 4; ++p) xv[p] = xrow[(size_t)p * HDIM + j];

    __syncthreads();

    int cur = 0;
    for (int t = 0; t < T; t += 4) {
#pragma unroll
        for (int p = 0; p < 4; ++p) {
            int tf = t + p + 4; tf = (tf < T) ? tf : (T - 1);
            const float xnew = xrow[(size_t)tf * HDIM + j];

            const float4* h4 = reinterpret_cast<const float4*>(&hbuf[cur][q * HQ]);
            float s0 = 0.f, s1 = 0.f, s2 = 0.f, s3 = 0.f;
#pragma unroll
            for (int c = 0; c < 8; ++c) {
                const uint4  wv = wp[c];
                const float4 hA = h4[2 * c + 0];
                const float4 hB = h4[2 * c + 1];
                s0 = dot2a(wv.x, pack2(hA.x, hA.y), s0);
                s1 = dot2a(wv.y, pack2(hA.z, hA.w), s1);
                s2 = dot2a(wv.z, pack2(hB.x, hB.y), s2);
                s3 = dot2a(wv.w, pack2(hB.z, hB.w), s3);
            }
            float s = (s0 + s1) + (s2 + s3);

            s += __shfl_xor(s, 1);
            s += __shfl_xor(s, 2);

            const float hn = fast_tanh(s + xv[p]);

            if (q == 0)      hbuf[cur ^ 1][hpos] = hn;
            else if (q == 1) yrow[(size_t)(t + p) * HDIM + j] = hn;

            xv[p] = xnew;
            cur ^= 1;
            __syncthreads();
        }
    }
}

// ---------------------------------------------------------------------------
// Fallback: exact R3 fp32 scan (proven 763 us) if ws lacks room for w16.
// ---------------------------------------------------------------------------
__global__ __launch_bounds__(1024, 4) void elman_scan_f32(
    const float* __restrict__ xp,
    const float* __restrict__ Whh,
    float* __restrict__ y,
    int T)
{
    const int b    = blockIdx.x;
    const int tid  = threadIdx.x;
    const int lane = tid & 63;
    const int wave = tid >> 6;
    const int j    = wave * 16 + (lane >> 2);
    const int q    = lane & 3;

    float4 w[16];
    {
        const float4* wp = reinterpret_cast<const float4*>(Whh + (size_t)j * HDIM + q * 64);
#pragma unroll
        for (int c = 0; c < 16; ++c) w[c] = wp[c];
    }

    __shared__ __align__(16) float hbuf[2][4 * HQ];

    const float* xrow = xp + (size_t)b * T * HDIM;
    float*       yrow = y  + (size_t)b * T * HDIM;

    const int hpos = (j >> 6) * HQ + (j & 63);
    if (q == 0) hbuf[0][hpos] = 0.f;

    float xv[4];
#pragma unroll
    for (int p = 0; p < 4; ++p) xv[p] = xrow[(size_t)p * HDIM + j];

    __syncthreads();

    int cur = 0;
    for (int t = 0; t < T; t += 4) {
#pragma unroll
        for (int p = 0; p < 4; ++p) {
            int tf = t + p + 4; tf = (tf < T) ? tf : (T - 1);
            const float xnew = xrow[(size_t)tf * HDIM + j];

            const float* hb = &hbuf[cur][q * HQ];
            float s0 = 0.f, s1 = 0.f, s2 = 0.f, s3 = 0.f;
#pragma unroll
            for (int c = 0; c < 16; c += 4) {
                const float4 h0 = *reinterpret_cast<const float4*>(hb + (c + 0) * 4);
                const float4 h1 = *reinterpret_cast<const float4*>(hb + (c + 1) * 4);
                const float4 h2 = *reinterpret_cast<const float4*>(hb + (c + 2) * 4);
                const float4 h3 = *reinterpret_cast<const float4*>(hb + (c + 3) * 4);
                s0 = fmaf(w[c + 0].x, h0.x, s0); s0 = fmaf(w[c + 0].y, h0.y, s0);
                s0 = fmaf(w[c + 0].z, h0.z, s0); s0 = fmaf(w[c + 0].w, h0.w, s0);
                s1 = fmaf(w[c + 1].x, h1.x, s1); s1 = fmaf(w[c + 1].y, h1.y, s1);
                s1 = fmaf(w[c + 1].z, h1.z, s1); s1 = fmaf(w[c + 1].w, h1.w, s1);
                s2 = fmaf(w[c + 2].x, h2.x, s2); s2 = fmaf(w[c + 2].y, h2.y, s2);
                s2 = fmaf(w[c + 2].z, h2.z, s2); s2 = fmaf(w[c + 2].w, h2.w, s2);
                s3 = fmaf(w[c + 3].x, h3.x, s3); s3 = fmaf(w[c + 3].y, h3.y, s3);
                s3 = fmaf(w[c + 3].z, h3.z, s3); s3 = fmaf(w[c + 3].w, h3.w, s3);
            }
            float s = (s0 + s1) + (s2 + s3);

            s += __shfl_xor(s, 1);
            s += __shfl_xor(s, 2);

            const float hn = fast_tanh(s + xv[p]);

            if (q == 0)      hbuf[cur ^ 1][hpos] = hn;
            else if (q == 1) yrow[(size_t)(t + p) * HDIM + j] = hn;

            xv[p] = xnew;
            cur ^= 1;
            __syncthreads();
        }
    }
}

// ---------------------------------------------------------------------------
extern "C" void kernel_launch(void* const* d_in, const int* in_sizes, int n_in,
                              void* d_out, int out_size, void* d_ws, size_t ws_size,
                              hipStream_t stream)
{
    const float* x     = (const float*)d_in[0];
    const float* W_ih0 = (const float*)d_in[1];
    const float* b_ih0 = (const float*)d_in[2];
    const float* W_hh0 = (const float*)d_in[3];
    const float* W_ih1 = (const float*)d_in[4];
    const float* b_ih1 = (const float*)d_in[5];
    const float* W_hh1 = (const float*)d_in[6];

    float* out = (float*)d_out;
    float* xp  = (float*)d_ws;                        // 64 MB

    const size_t XPB   = (size_t)BATCH * TLEN * HDIM * sizeof(float);
    const size_t WELEM = (size_t)HDIM * HDIM;         // 64K halfs = 128 KB
    const bool   f16ok = ws_size >= XPB + 2 * WELEM * sizeof(uint16_t);

    uint16_t* w16a = (uint16_t*)((char*)d_ws + XPB);
    uint16_t* w16b = w16a + WELEM;

    const int M = BATCH * TLEN;
    dim3 ggrid(M / 128, HDIM / 64);

    if (f16ok) {
        conv_w16<<<HDIM * HDIM / 256, 256, 0, stream>>>(W_hh0, w16a);
        conv_w16<<<HDIM * HDIM / 256, 256, 0, stream>>>(W_hh1, w16b);
        proj_gemm<<<ggrid, 256, 0, stream>>>(x,   W_ih0, b_ih0, xp, M);
        elman_scan_f16<<<BATCH, 1024, 0, stream>>>(xp, w16a, out, TLEN);
        proj_gemm<<<ggrid, 256, 0, stream>>>(out, W_ih1, b_ih1, xp, M);
        elman_scan_f16<<<BATCH, 1024, 0, stream>>>(xp, w16b, out, TLEN);
    } else {
        proj_gemm<<<ggrid, 256, 0, stream>>>(x,   W_ih0, b_ih0, xp, M);
        elman_scan_f32<<<BATCH, 1024, 0, stream>>>(xp, W_hh0, out, TLEN);
        proj_gemm<<<ggrid, 256, 0, stream>>>(out, W_ih1, b_ih1, xp, M);
        elman_scan_f32<<<BATCH, 1024, 0, stream>>>(xp, W_hh1, out, TLEN);
    }
}